// Round 1
// baseline (8366.473 us; speedup 1.0000x reference)
//
#include <hip/hip_runtime.h>
#include <hip/hip_bf16.h>
#include <math.h>

#define N_EMBD 768
#define N_EXP  8
#define DIMH   2048
#define BB     8
#define CAPN   1024
#define M_TOT  (BB*CAPN)   // 8192 rows per expert

// ---------------------------------------------------------------------------
// Kernel 0: per-row scale factor  s[e*8192+m] = sqrt(768) / max(||x_row||, 1e-12)
// One wave (64 lanes) per row.
// ---------------------------------------------------------------------------
__global__ void rownorm_kernel(const float* __restrict__ x, float* __restrict__ s) {
    int w    = (blockIdx.x * blockDim.x + threadIdx.x) >> 6;   // global wave id
    int lane = threadIdx.x & 63;
    if (w >= N_EXP * M_TOT) return;
    int e = w >> 13;           // / 8192
    int m = w & 8191;
    int b = m >> 10, n = m & 1023;
    const float* row = x + (size_t)((b * N_EXP + e) * CAPN + n) * N_EMBD;
    float acc = 0.f;
#pragma unroll
    for (int i = 0; i < N_EMBD / 64; ++i) {
        float v = row[lane + i * 64];
        acc += v * v;
    }
#pragma unroll
    for (int off = 32; off >= 1; off >>= 1) acc += __shfl_down(acc, off, 64);
    if (lane == 0) {
        float l2 = sqrtf(acc);
        s[w] = 27.712812921102035f / fmaxf(l2, 1e-12f);  // sqrt(768)/max(l2,eps)
    }
}

// ---------------------------------------------------------------------------
// Kernel 1: per-expert fused GEMM1 + GLU epilogue.
//   u = h @ c_fc  (h = x * s * gamma), v = u[:, :2048], gate = u[:, 2048:]
//   g = gelu_exact(gate) * v * mult_bias      -> g buffer (8192 x 2048) fp32
// 64(rows) x 64(cols, doubled v+gate) tile, 256 threads, 4x4(v)+4x4(gate)/thread.
// ---------------------------------------------------------------------------
__global__ __launch_bounds__(256) void gemm1_kernel(
        const float* __restrict__ x, const float* __restrict__ cfc,
        const float* __restrict__ gamma, const float* __restrict__ mbias,
        const float* __restrict__ s, float* __restrict__ g, int e) {
    __shared__ __align__(16) float As[16][64];     // [k][m]
    __shared__ __align__(16) float Bs[16][128];    // [k][c]  c<64: v cols, c>=64: gate cols

    int t  = threadIdx.x;
    int j0 = blockIdx.x * 64;
    int m0 = blockIdx.y * 64;
    int tx = t & 15, ty = t >> 4;

    float av[4][4] = {{0}}, ag[4][4] = {{0}};

    // A staging indices: thread t loads row am, 4 consecutive k at ak
    int am = t >> 2;
    int ak = (t & 3) * 4;
    int gm = m0 + am;
    int b = gm >> 10, n = gm & 1023;
    const float* arow = x + (size_t)((b * N_EXP + e) * CAPN + n) * N_EMBD;
    float srow = s[e * M_TOT + gm];

    // B staging indices: thread t loads k-row bk, 4 consecutive cols at bc (v and gate)
    int bk = t >> 4;
    int bc = (t & 15) * 4;
    const float* cbase = cfc + (size_t)e * N_EMBD * (2 * DIMH);

    for (int k0 = 0; k0 < N_EMBD; k0 += 16) {
        float4 a4 = *(const float4*)(arow + k0 + ak);
        float4 g4 = *(const float4*)(gamma + k0 + ak);
        As[ak + 0][am] = a4.x * g4.x * srow;
        As[ak + 1][am] = a4.y * g4.y * srow;
        As[ak + 2][am] = a4.z * g4.z * srow;
        As[ak + 3][am] = a4.w * g4.w * srow;

        const float* brow = cbase + (size_t)(k0 + bk) * (2 * DIMH);
        *(float4*)&Bs[bk][bc]      = *(const float4*)(brow + j0 + bc);
        *(float4*)&Bs[bk][64 + bc] = *(const float4*)(brow + DIMH + j0 + bc);
        __syncthreads();

#pragma unroll
        for (int k = 0; k < 16; ++k) {
            float4 a  = *(const float4*)&As[k][ty * 4];
            float4 bv = *(const float4*)&Bs[k][tx * 4];
            float4 bg = *(const float4*)&Bs[k][64 + tx * 4];
            float aa[4] = {a.x, a.y, a.z, a.w};
            float vv[4] = {bv.x, bv.y, bv.z, bv.w};
            float gg[4] = {bg.x, bg.y, bg.z, bg.w};
#pragma unroll
            for (int i = 0; i < 4; ++i) {
#pragma unroll
                for (int j = 0; j < 4; ++j) {
                    av[i][j] += aa[i] * vv[j];
                    ag[i][j] += aa[i] * gg[j];
                }
            }
        }
        __syncthreads();
    }

    // Epilogue: g = gelu_exact(gate) * v * mult_bias
#pragma unroll
    for (int i = 0; i < 4; ++i) {
        int m = m0 + ty * 4 + i;
        float res[4];
#pragma unroll
        for (int j = 0; j < 4; ++j) {
            float gt = ag[i][j];
            float ge = 0.5f * gt * (1.0f + erff(gt * 0.70710678118654752f));
            res[j] = ge * av[i][j] * mbias[j0 + tx * 4 + j];
        }
        float4 o = {res[0], res[1], res[2], res[3]};
        *(float4*)(g + (size_t)m * DIMH + j0 + tx * 4) = o;
    }
}

// ---------------------------------------------------------------------------
// Kernel 2: per-expert GEMM2: out = g @ c_proj, written to (B,E,CAP,D) layout.
// ---------------------------------------------------------------------------
__global__ __launch_bounds__(256) void gemm2_kernel(
        const float* __restrict__ g, const float* __restrict__ cproj,
        float* __restrict__ out, int e) {
    __shared__ __align__(16) float As[16][64];   // [k][m]
    __shared__ __align__(16) float Bs[16][64];   // [k][d]

    int t  = threadIdx.x;
    int d0 = blockIdx.x * 64;
    int m0 = blockIdx.y * 64;
    int tx = t & 15, ty = t >> 4;

    float acc[4][4] = {{0}};

    int am = t >> 2;
    int ak = (t & 3) * 4;
    const float* arow = g + (size_t)(m0 + am) * DIMH;

    int bk = t >> 4;
    int bd = (t & 15) * 4;
    const float* cbase = cproj + (size_t)e * DIMH * N_EMBD;

    for (int k0 = 0; k0 < DIMH; k0 += 16) {
        float4 a4 = *(const float4*)(arow + k0 + ak);
        As[ak + 0][am] = a4.x;
        As[ak + 1][am] = a4.y;
        As[ak + 2][am] = a4.z;
        As[ak + 3][am] = a4.w;
        *(float4*)&Bs[bk][bd] = *(const float4*)(cbase + (size_t)(k0 + bk) * N_EMBD + d0 + bd);
        __syncthreads();

#pragma unroll
        for (int k = 0; k < 16; ++k) {
            float4 a  = *(const float4*)&As[k][ty * 4];
            float4 bb = *(const float4*)&Bs[k][tx * 4];
            float aa[4] = {a.x, a.y, a.z, a.w};
            float bv[4] = {bb.x, bb.y, bb.z, bb.w};
#pragma unroll
            for (int i = 0; i < 4; ++i) {
#pragma unroll
                for (int j = 0; j < 4; ++j) acc[i][j] += aa[i] * bv[j];
            }
        }
        __syncthreads();
    }

#pragma unroll
    for (int i = 0; i < 4; ++i) {
        int m = m0 + ty * 4 + i;
        int b = m >> 10, n = m & 1023;
        float4 o = {acc[i][0], acc[i][1], acc[i][2], acc[i][3]};
        *(float4*)(out + (size_t)((b * N_EXP + e) * CAPN + n) * N_EMBD + d0 + tx * 4) = o;
    }
}

// ---------------------------------------------------------------------------
extern "C" void kernel_launch(void* const* d_in, const int* in_sizes, int n_in,
                              void* d_out, int out_size, void* d_ws, size_t ws_size,
                              hipStream_t stream) {
    const float* x     = (const float*)d_in[0];
    const float* cfc   = (const float*)d_in[1];
    const float* cproj = (const float*)d_in[2];
    const float* gamma = (const float*)d_in[3];
    const float* mbias = (const float*)d_in[4];
    float* out = (float*)d_out;

    // ws layout: [0, 256KB): row scales s (65536 floats); [256KB, +64MB): g buffer
    float* s = (float*)d_ws;
    float* g = (float*)((char*)d_ws + 262144);

    rownorm_kernel<<<dim3(16384), dim3(256), 0, stream>>>(x, s);

    for (int e = 0; e < N_EXP; ++e) {
        gemm1_kernel<<<dim3(32, 128), dim3(256), 0, stream>>>(x, cfc, gamma, mbias, s, g, e);
        gemm2_kernel<<<dim3(12, 128), dim3(256), 0, stream>>>(g, cproj, out, e);
    }
}

// Round 2
// 1508.509 us; speedup vs baseline: 5.5462x; 5.5462x over previous
//
#include <hip/hip_runtime.h>
#include <math.h>

#define N_EMBD 768
#define N_EXP  8
#define DIMH   2048
#define CAPN   1024
#define M_TOT  8192          // rows per expert (B*CAP)
#define BK     32            // K-tile (one MFMA K per quad set)

typedef __bf16 bf16x8 __attribute__((ext_vector_type(8)));
typedef float  f32x4  __attribute__((ext_vector_type(4)));

__device__ __forceinline__ unsigned short f2bf(float f) {
    unsigned int u = __float_as_uint(f);
    unsigned int r = (u + 0x7fffu + ((u >> 16) & 1u)) >> 16;
    return (unsigned short)r;
}

__device__ __forceinline__ void gload16(const void* g, void* l) {
    __builtin_amdgcn_global_load_lds(
        (const __attribute__((address_space(1))) unsigned int*)g,
        (__attribute__((address_space(3))) unsigned int*)l, 16, 0, 0);
}

__device__ __forceinline__ int swz(int m) { return (m ^ (m >> 2)) & 3; }

// ---------------------------------------------------------------------------
// Kernel A: per-row L2 norm + scale + gamma + fp32->bf16.  One block per row.
// x: (B=8, E=8, CAP=1024, 768) fp32  ->  h: [E][8192][768] bf16
// ---------------------------------------------------------------------------
__global__ __launch_bounds__(256) void norm_convert_kernel(
        const float* __restrict__ x, const float* __restrict__ gamma,
        unsigned short* __restrict__ h) {
    int r = blockIdx.x;                 // 0..65535
    int e = r >> 13, m = r & 8191;
    int b = m >> 10, nc = m & 1023;
    const float* row = x + (size_t)((b * N_EXP + e) * CAPN + nc) * N_EMBD;
    unsigned short* orow = h + (size_t)(e * M_TOT + m) * N_EMBD;
    int t = threadIdx.x;

    float v0 = row[t], v1 = row[t + 256], v2 = row[t + 512];
    float acc = v0 * v0 + v1 * v1 + v2 * v2;
#pragma unroll
    for (int off = 32; off >= 1; off >>= 1) acc += __shfl_down(acc, off, 64);
    __shared__ float part[4];
    if ((t & 63) == 0) part[t >> 6] = acc;
    __syncthreads();
    float tot = part[0] + part[1] + part[2] + part[3];
    float s = 27.712812921102035f / fmaxf(sqrtf(tot), 1e-12f);

    orow[t]       = f2bf(v0 * s * gamma[t]);
    orow[t + 256] = f2bf(v1 * s * gamma[t + 256]);
    orow[t + 512] = f2bf(v2 * s * gamma[t + 512]);
}

// ---------------------------------------------------------------------------
// Kernel B: transpose + convert weights.  in: [z][R][C] fp32 -> out: [z][C][R] bf16
// ---------------------------------------------------------------------------
__global__ __launch_bounds__(256) void transpose_convert_kernel(
        const float* __restrict__ in, unsigned short* __restrict__ out, int R, int C) {
    __shared__ float tile[32][33];
    int c0 = blockIdx.x * 32, r0 = blockIdx.y * 32;
    const float* ip = in + (size_t)blockIdx.z * R * C;
    unsigned short* op = out + (size_t)blockIdx.z * R * C;
    int tx = threadIdx.x & 31, ty = threadIdx.x >> 5;
#pragma unroll
    for (int i = 0; i < 4; ++i)
        tile[ty + 8 * i][tx] = ip[(size_t)(r0 + ty + 8 * i) * C + c0 + tx];
    __syncthreads();
#pragma unroll
    for (int i = 0; i < 4; ++i)
        op[(size_t)(c0 + ty + 8 * i) * R + r0 + tx] = f2bf(tile[tx][ty + 8 * i]);
}

// ---------------------------------------------------------------------------
// Kernel C: GEMM1 + GLU epilogue (per expert).
//   u_v = h @ cfcT_v^T, u_g = h @ cfcT_g^T ; g = gelu(u_g)*u_v*mbias -> bf16
// Tile: BM=128 x BN=64(v)+64(gate), BK=32. 256 thr = 4 waves, wave tile 64x32.
// ---------------------------------------------------------------------------
__global__ __launch_bounds__(256) void gemm1_kernel(
        const unsigned short* __restrict__ h,      // [8192][768] expert base
        const unsigned short* __restrict__ bT,     // [4096][768] expert base
        const float* __restrict__ mbias,           // [2048]
        unsigned short* __restrict__ g) {          // [8192][2048]
    __shared__ __align__(16) unsigned short sA[128 * BK];
    __shared__ __align__(16) unsigned short sBv[64 * BK];
    __shared__ __align__(16) unsigned short sBg[64 * BK];

    int t = threadIdx.x;
    int m0 = blockIdx.y * 128;
    int n0 = blockIdx.x * 64;

    // staging source pointers (advance by BK per step)
    int gr0 = t, gr1 = t + 256;
    int am0 = gr0 >> 2, am1 = gr1 >> 2;
    const unsigned short* gA0 = h + (size_t)(m0 + am0) * N_EMBD + (((gr0 & 3) ^ swz(am0)) * 8);
    const unsigned short* gA1 = h + (size_t)(m0 + am1) * N_EMBD + (((gr1 & 3) ^ swz(am1)) * 8);
    int bn = t >> 2;
    int bkc = ((t & 3) ^ swz(bn)) * 8;
    const unsigned short* gBv = bT + (size_t)(n0 + bn) * N_EMBD + bkc;
    const unsigned short* gBg = bT + (size_t)(DIMH + n0 + bn) * N_EMBD + bkc;
    unsigned short* lA0 = sA + gr0 * 8;
    unsigned short* lA1 = sA + gr1 * 8;
    unsigned short* lBv = sBv + t * 8;
    unsigned short* lBg = sBg + t * 8;

    // wave fragment offsets
    int w = t >> 6, lane = t & 63, lo = lane & 15, quad = lane >> 4;
    int wm = (w & 1) * 64, wn = (w >> 1) * 32;
    int aoff[4], boff[2];
#pragma unroll
    for (int i = 0; i < 4; ++i) {
        int m = wm + i * 16 + lo;
        aoff[i] = (m * 4 + (quad ^ swz(m))) * 8;
    }
#pragma unroll
    for (int j = 0; j < 2; ++j) {
        int n = wn + j * 16 + lo;
        boff[j] = (n * 4 + (quad ^ swz(n))) * 8;
    }

    f32x4 accv[4][2], accg[4][2];
#pragma unroll
    for (int i = 0; i < 4; ++i)
#pragma unroll
        for (int j = 0; j < 2; ++j) { accv[i][j] = (f32x4)0.f; accg[i][j] = (f32x4)0.f; }

    for (int k0 = 0; k0 < N_EMBD; k0 += BK) {
        gload16(gA0, lA0);
        gload16(gA1, lA1);
        gload16(gBv, lBv);
        gload16(gBg, lBg);
        gA0 += BK; gA1 += BK; gBv += BK; gBg += BK;
        __syncthreads();

        bf16x8 af[4], bv[2], bg[2];
#pragma unroll
        for (int i = 0; i < 4; ++i) af[i] = *(const bf16x8*)(sA + aoff[i]);
#pragma unroll
        for (int j = 0; j < 2; ++j) {
            bv[j] = *(const bf16x8*)(sBv + boff[j]);
            bg[j] = *(const bf16x8*)(sBg + boff[j]);
        }
#pragma unroll
        for (int i = 0; i < 4; ++i)
#pragma unroll
            for (int j = 0; j < 2; ++j) {
                accv[i][j] = __builtin_amdgcn_mfma_f32_16x16x32_bf16(af[i], bv[j], accv[i][j], 0, 0, 0);
                accg[i][j] = __builtin_amdgcn_mfma_f32_16x16x32_bf16(af[i], bg[j], accg[i][j], 0, 0, 0);
            }
        __syncthreads();
    }

    // epilogue: g = gelu_exact(gate) * v * mbias  (C/D: col=lane&15, row=quad*4+reg)
#pragma unroll
    for (int j = 0; j < 2; ++j) {
        int n = n0 + wn + j * 16 + lo;
        float mb = mbias[n];
#pragma unroll
        for (int i = 0; i < 4; ++i) {
            int mrow = m0 + wm + i * 16 + quad * 4;
#pragma unroll
            for (int r = 0; r < 4; ++r) {
                float gt = accg[i][j][r];
                float ge = 0.5f * gt * (1.0f + erff(gt * 0.70710678118654752f));
                g[(size_t)(mrow + r) * DIMH + n] = f2bf(ge * accv[i][j][r] * mb);
            }
        }
    }
}

// ---------------------------------------------------------------------------
// Kernel D: GEMM2 (per expert): out = g @ cprojT^T, scattered to (B,E,CAP,D).
// Tile: BM=128 x BN=64, BK=32, K=2048.
// ---------------------------------------------------------------------------
__global__ __launch_bounds__(256) void gemm2_kernel(
        const unsigned short* __restrict__ g,      // [8192][2048]
        const unsigned short* __restrict__ bT,     // [768][2048] expert base
        float* __restrict__ out, int e) {
    __shared__ __align__(16) unsigned short sA[128 * BK];
    __shared__ __align__(16) unsigned short sB[64 * BK];

    int t = threadIdx.x;
    int m0 = blockIdx.y * 128;
    int n0 = blockIdx.x * 64;

    int gr0 = t, gr1 = t + 256;
    int am0 = gr0 >> 2, am1 = gr1 >> 2;
    const unsigned short* gA0 = g + (size_t)(m0 + am0) * DIMH + (((gr0 & 3) ^ swz(am0)) * 8);
    const unsigned short* gA1 = g + (size_t)(m0 + am1) * DIMH + (((gr1 & 3) ^ swz(am1)) * 8);
    int bn = t >> 2;
    const unsigned short* gB = bT + (size_t)(n0 + bn) * DIMH + (((t & 3) ^ swz(bn)) * 8);
    unsigned short* lA0 = sA + gr0 * 8;
    unsigned short* lA1 = sA + gr1 * 8;
    unsigned short* lB = sB + t * 8;

    int w = t >> 6, lane = t & 63, lo = lane & 15, quad = lane >> 4;
    int wm = (w & 1) * 64, wn = (w >> 1) * 32;
    int aoff[4], boff[2];
#pragma unroll
    for (int i = 0; i < 4; ++i) {
        int m = wm + i * 16 + lo;
        aoff[i] = (m * 4 + (quad ^ swz(m))) * 8;
    }
#pragma unroll
    for (int j = 0; j < 2; ++j) {
        int n = wn + j * 16 + lo;
        boff[j] = (n * 4 + (quad ^ swz(n))) * 8;
    }

    f32x4 acc[4][2];
#pragma unroll
    for (int i = 0; i < 4; ++i)
#pragma unroll
        for (int j = 0; j < 2; ++j) acc[i][j] = (f32x4)0.f;

    for (int k0 = 0; k0 < DIMH; k0 += BK) {
        gload16(gA0, lA0);
        gload16(gA1, lA1);
        gload16(gB, lB);
        gA0 += BK; gA1 += BK; gB += BK;
        __syncthreads();

        bf16x8 af[4], bf[2];
#pragma unroll
        for (int i = 0; i < 4; ++i) af[i] = *(const bf16x8*)(sA + aoff[i]);
#pragma unroll
        for (int j = 0; j < 2; ++j) bf[j] = *(const bf16x8*)(sB + boff[j]);
#pragma unroll
        for (int i = 0; i < 4; ++i)
#pragma unroll
            for (int j = 0; j < 2; ++j)
                acc[i][j] = __builtin_amdgcn_mfma_f32_16x16x32_bf16(af[i], bf[j], acc[i][j], 0, 0, 0);
        __syncthreads();
    }

#pragma unroll
    for (int i = 0; i < 4; ++i) {
#pragma unroll
        for (int r = 0; r < 4; ++r) {
            int m = m0 + wm + i * 16 + quad * 4 + r;
            int b = m >> 10, nc = m & 1023;
            float* orow = out + (size_t)((b * N_EXP + e) * CAPN + nc) * N_EMBD;
#pragma unroll
            for (int j = 0; j < 2; ++j)
                orow[n0 + wn + j * 16 + lo] = acc[i][j][r];
        }
    }
}

// ---------------------------------------------------------------------------
extern "C" void kernel_launch(void* const* d_in, const int* in_sizes, int n_in,
                              void* d_out, int out_size, void* d_ws, size_t ws_size,
                              hipStream_t stream) {
    const float* x     = (const float*)d_in[0];
    const float* cfc   = (const float*)d_in[1];
    const float* cproj = (const float*)d_in[2];
    const float* gamma = (const float*)d_in[3];
    const float* mbias = (const float*)d_in[4];
    float* out = (float*)d_out;

    // ws layout (bytes): h bf16 [8][8192][768]           @ 0        (100663296)
    //                    cfcT bf16 [8][4096][768]        @ h_end    ( 50331648)
    //                    cprojT bf16 [8][768][2048]      @ +        ( 25165824)
    //                    g bf16 [8192][2048] (per-expert)@ +        ( 33554432)
    unsigned short* h      = (unsigned short*)d_ws;
    unsigned short* cfcT   = h + (size_t)N_EXP * M_TOT * N_EMBD;
    unsigned short* cprojT = cfcT + (size_t)N_EXP * 2 * DIMH * N_EMBD;
    unsigned short* gbuf   = cprojT + (size_t)N_EXP * DIMH * N_EMBD;

    norm_convert_kernel<<<dim3(N_EXP * M_TOT), dim3(256), 0, stream>>>(x, gamma, h);
    transpose_convert_kernel<<<dim3(2 * DIMH / 32, N_EMBD / 32, N_EXP), dim3(256), 0, stream>>>(
        cfc, cfcT, N_EMBD, 2 * DIMH);
    transpose_convert_kernel<<<dim3(N_EMBD / 32, DIMH / 32, N_EXP), dim3(256), 0, stream>>>(
        cproj, cprojT, DIMH, N_EMBD);

    for (int e = 0; e < N_EXP; ++e) {
        const unsigned short* he  = h + (size_t)e * M_TOT * N_EMBD;
        const unsigned short* fce = cfcT + (size_t)e * 2 * DIMH * N_EMBD;
        const unsigned short* pje = cprojT + (size_t)e * DIMH * N_EMBD;
        gemm1_kernel<<<dim3(DIMH / 64, M_TOT / 128), dim3(256), 0, stream>>>(he, fce, mbias, gbuf);
        gemm2_kernel<<<dim3(N_EMBD / 64, M_TOT / 128), dim3(256), 0, stream>>>(gbuf, pje, out, e);
    }
}